// Round 1
// baseline (79.820 us; speedup 1.0000x reference)
//
#include <hip/hip_runtime.h>
#include <float.h>

// Problem constants (match reference)
#define BB 32
#define CC 256
#define SS 64
#define IMG (SS * SS)          // 4096 pixels per (b,c) image
#define NPIX (BB * IMG)        // 131072 per-batch-pixel count
#define NTOT (BB * CC * IMG)   // 33554432 total elements

__device__ __forceinline__ float4 f4max(float4 a, float4 b) {
    return make_float4(fmaxf(a.x, b.x), fmaxf(a.y, b.y), fmaxf(a.z, b.z), fmaxf(a.w, b.w));
}
__device__ __forceinline__ float4 f4add(float4 a, float4 b) {
    return make_float4(a.x + b.x, a.y + b.y, a.z + b.z, a.w + b.w);
}

// ---------------- Kernel 1: channel reduction ----------------
// Block: 256 threads = 4 waves. Block owns 256 contiguous pixels of one batch.
// Wave w owns channels [w*64, w*64+64). Each lane holds a float4 (4 pixels).
// Combine the 4 waves' partials through LDS; wave 0 writes sp_max / sp_mean.
__global__ __launch_bounds__(256) void reduce_c_kernel(const float* __restrict__ x,
                                                       float* __restrict__ sp_max,
                                                       float* __restrict__ sp_mean) {
    const int blk   = blockIdx.x;       // 512 blocks: 16 per batch
    const int b     = blk >> 4;
    const int chunk = blk & 15;
    const int tid   = threadIdx.x;
    const int wave  = tid >> 6;
    const int lane  = tid & 63;
    const int pos   = (chunk << 8) + (lane << 2);   // pixel index within image, float4-aligned

    const float* xp = x + ((size_t)(b * CC + wave * 64) << 12) + pos;

    float4 vmax = make_float4(-FLT_MAX, -FLT_MAX, -FLT_MAX, -FLT_MAX);
    float4 vsum = make_float4(0.f, 0.f, 0.f, 0.f);
#pragma unroll 8
    for (int c = 0; c < 64; ++c) {
        float4 v = *(const float4*)(xp + ((size_t)c << 12));
        vmax = f4max(vmax, v);
        vsum = f4add(vsum, v);
    }

    __shared__ float4 smax[4][64];
    __shared__ float4 ssum[4][64];
    smax[wave][lane] = vmax;
    ssum[wave][lane] = vsum;
    __syncthreads();

    if (wave == 0) {
        float4 m = smax[0][lane];
        float4 s = ssum[0][lane];
#pragma unroll
        for (int w = 1; w < 4; ++w) {
            m = f4max(m, smax[w][lane]);
            s = f4add(s, ssum[w][lane]);
        }
        const float inv = 1.0f / (float)CC;
        float4 mn = make_float4(s.x * inv, s.y * inv, s.z * inv, s.w * inv);
        *(float4*)(sp_max + (size_t)b * IMG + pos) = m;
        *(float4*)(sp_mean + (size_t)b * IMG + pos) = mn;
    }
}

// ---------------- Kernel 2: branch math + spatial tile ----------------
__device__ __forceinline__ float allreduce_sum(float v) {
#pragma unroll
    for (int o = 32; o > 0; o >>= 1) v += __shfl_xor(v, o);
    return v;
}
__device__ __forceinline__ float allreduce_max(float v) {
#pragma unroll
    for (int o = 32; o > 0; o >>= 1) v = fmaxf(v, __shfl_xor(v, o));
    return v;
}

__device__ __forceinline__ float branch_lane(float meanv, float maxv,
                                             float w0, float w1, float w2,
                                             float b0, float b1, float b2) {
    // softmax over the 64 lanes
    float m  = allreduce_max(meanv);
    float e  = expf(meanv - m);
    float s  = e / allreduce_sum(e);
    float y0 = allreduce_sum(meanv * w0);
    float y1 = allreduce_sum(maxv * w1);
    float y0t = tanhf(fmaf(y0, s, b0));
    float y1t = tanhf(fmaf(y1, s, b1));
    float yw2 = allreduce_sum(y1t * w2);
    return fmaf(yw2, y0t, b2);
}

__global__ __launch_bounds__(64) void branch_kernel(
        const float* __restrict__ sp_max, const float* __restrict__ sp_mean,
        const float* __restrict__ ww0, const float* __restrict__ ww1, const float* __restrict__ ww2,
        const float* __restrict__ wb0, const float* __restrict__ wb1, const float* __restrict__ wb2,
        const float* __restrict__ hw0, const float* __restrict__ hw1, const float* __restrict__ hw2,
        const float* __restrict__ hb0, const float* __restrict__ hb1, const float* __restrict__ hb2,
        float* __restrict__ spatial) {
    const int b = blockIdx.x;
    const int t = threadIdx.x;          // lane 0..63, one wave per batch
    const float* smx = sp_max + (size_t)b * IMG;
    const float* smn = sp_mean + (size_t)b * IMG;

    // width reductions: over h (column t), coalesced across lanes
    float wmax = -FLT_MAX, wsum = 0.f;
    // height reductions: over w (row t)
    float hmax = -FLT_MAX, hsum = 0.f;
#pragma unroll 4
    for (int i = 0; i < 64; ++i) {
        wmax = fmaxf(wmax, smx[i * 64 + t]);
        wsum += smn[i * 64 + t];
        hmax = fmaxf(hmax, smx[t * 64 + i]);
        hsum += smn[t * 64 + i];
    }
    const float inv = 1.0f / (float)SS;
    float y_w = branch_lane(wsum * inv, wmax, ww0[t], ww1[t], ww2[t], wb0[t], wb1[t], wb2[t]);
    float y_h = branch_lane(hsum * inv, hmax, hw0[t], hw1[t], hw2[t], hb0[t], hb1[t], hb2[t]);

    __shared__ float sh_h[64];
    sh_h[t] = y_h;
    __syncthreads();

    float* sp = spatial + (size_t)b * IMG;
#pragma unroll 4
    for (int h = 0; h < 64; ++h) {
        sp[h * 64 + t] = tanhf(sh_h[h] * y_w);   // coalesced store
    }
}

// ---------------- Kernel 3: apply ----------------
__global__ __launch_bounds__(256) void apply_kernel(const float* __restrict__ x,
                                                    const float* __restrict__ spatial,
                                                    float* __restrict__ out) {
    const int n4 = NTOT / 4;
    const int stride = gridDim.x * blockDim.x;
    for (int i = blockIdx.x * blockDim.x + threadIdx.x; i < n4; i += stride) {
        const size_t base = (size_t)i << 2;            // float index
        float4 xv = ((const float4*)x)[i];
        const size_t b   = base >> 20;                 // / (C*IMG)
        const size_t pos = base & (IMG - 1);           // index within image
        float4 sv = *(const float4*)(spatial + (b << 12) + pos);
        float4 ov = make_float4(xv.x * (sv.x + 1.0f), xv.y * (sv.y + 1.0f),
                                xv.z * (sv.z + 1.0f), xv.w * (sv.w + 1.0f));
        ((float4*)out)[i] = ov;
    }
}

extern "C" void kernel_launch(void* const* d_in, const int* in_sizes, int n_in,
                              void* d_out, int out_size, void* d_ws, size_t ws_size,
                              hipStream_t stream) {
    const float* x   = (const float*)d_in[0];
    const float* ww0 = (const float*)d_in[1];
    const float* ww1 = (const float*)d_in[2];
    const float* ww2 = (const float*)d_in[3];
    const float* wb0 = (const float*)d_in[4];
    const float* wb1 = (const float*)d_in[5];
    const float* wb2 = (const float*)d_in[6];
    const float* hw0 = (const float*)d_in[7];
    const float* hw1 = (const float*)d_in[8];
    const float* hw2 = (const float*)d_in[9];
    const float* hb0 = (const float*)d_in[10];
    const float* hb1 = (const float*)d_in[11];
    const float* hb2 = (const float*)d_in[12];
    float* out = (float*)d_out;

    float* sp_max  = (float*)d_ws;                 // NPIX floats
    float* sp_mean = sp_max + NPIX;                // NPIX floats
    float* spatial = sp_mean + NPIX;               // NPIX floats

    reduce_c_kernel<<<NPIX / 256, 256, 0, stream>>>(x, sp_max, sp_mean);
    branch_kernel<<<BB, 64, 0, stream>>>(sp_max, sp_mean,
                                         ww0, ww1, ww2, wb0, wb1, wb2,
                                         hw0, hw1, hw2, hb0, hb1, hb2, spatial);
    apply_kernel<<<2048, 256, 0, stream>>>(x, spatial, out);
}

// Round 5
// 78.567 us; speedup vs baseline: 1.0159x; 1.0159x over previous
//
#include <hip/hip_runtime.h>
#include <float.h>

// Problem constants (match reference)
#define BB 32
#define CC 256
#define SS 64
#define IMG (SS * SS)          // 4096 pixels per (b,c) image
#define NPIX (BB * IMG)        // 131072 per-batch-pixel count
#define NTOT (BB * CC * IMG)   // 33554432 total elements

typedef float f32x4 __attribute__((ext_vector_type(4)));   // clang-native vec4 (nontemporal-builtin compatible)

__device__ __forceinline__ f32x4 f4max(f32x4 a, f32x4 b) {
    f32x4 r;
    r.x = fmaxf(a.x, b.x); r.y = fmaxf(a.y, b.y);
    r.z = fmaxf(a.z, b.z); r.w = fmaxf(a.w, b.w);
    return r;
}

// ---------------- Kernel 1: channel reduction ----------------
// Block: 256 threads = 4 waves. Block owns 256 contiguous pixels of one batch.
// Wave w owns channels [w*64, w*64+64). Each lane holds a float4 (4 pixels).
__global__ __launch_bounds__(256) void reduce_c_kernel(const float* __restrict__ x,
                                                       float* __restrict__ sp_max,
                                                       float* __restrict__ sp_mean) {
    const int blk   = blockIdx.x;       // 512 blocks: 16 per batch
    const int b     = blk >> 4;
    const int chunk = blk & 15;
    const int tid   = threadIdx.x;
    const int wave  = tid >> 6;
    const int lane  = tid & 63;
    const int pos   = (chunk << 8) + (lane << 2);   // pixel index within image, float4-aligned

    const float* xp = x + ((size_t)(b * CC + wave * 64) << 12) + pos;

    f32x4 vmax = (f32x4)(-FLT_MAX);
    f32x4 vsum = (f32x4)(0.f);
#pragma unroll 16
    for (int c = 0; c < 64; ++c) {
        f32x4 v = *(const f32x4*)(xp + ((size_t)c << 12));
        vmax = f4max(vmax, v);
        vsum += v;
    }

    __shared__ f32x4 smax[4][64];
    __shared__ f32x4 ssum[4][64];
    smax[wave][lane] = vmax;
    ssum[wave][lane] = vsum;
    __syncthreads();

    if (wave == 0) {
        f32x4 m = smax[0][lane];
        f32x4 s = ssum[0][lane];
#pragma unroll
        for (int w = 1; w < 4; ++w) {
            m = f4max(m, smax[w][lane]);
            s += ssum[w][lane];
        }
        const float inv = 1.0f / (float)CC;
        f32x4 mn = s * inv;
        *(f32x4*)(sp_max + (size_t)b * IMG + pos) = m;
        *(f32x4*)(sp_mean + (size_t)b * IMG + pos) = mn;
    }
}

// ---------------- Kernel 2: branch math + spatial tile ----------------
__device__ __forceinline__ float allreduce_sum(float v) {
#pragma unroll
    for (int o = 32; o > 0; o >>= 1) v += __shfl_xor(v, o);
    return v;
}
__device__ __forceinline__ float allreduce_max(float v) {
#pragma unroll
    for (int o = 32; o > 0; o >>= 1) v = fmaxf(v, __shfl_xor(v, o));
    return v;
}

__device__ __forceinline__ float branch_lane(float meanv, float maxv,
                                             float w0, float w1, float w2,
                                             float b0, float b1, float b2) {
    // softmax over the 64 lanes
    float m  = allreduce_max(meanv);
    float e  = expf(meanv - m);
    float s  = e / allreduce_sum(e);
    float y0 = allreduce_sum(meanv * w0);
    float y1 = allreduce_sum(maxv * w1);
    float y0t = tanhf(fmaf(y0, s, b0));
    float y1t = tanhf(fmaf(y1, s, b1));
    float yw2 = allreduce_sum(y1t * w2);
    return fmaf(yw2, y0t, b2);
}

__global__ __launch_bounds__(64) void branch_kernel(
        const float* __restrict__ sp_max, const float* __restrict__ sp_mean,
        const float* __restrict__ ww0, const float* __restrict__ ww1, const float* __restrict__ ww2,
        const float* __restrict__ wb0, const float* __restrict__ wb1, const float* __restrict__ wb2,
        const float* __restrict__ hw0, const float* __restrict__ hw1, const float* __restrict__ hw2,
        const float* __restrict__ hb0, const float* __restrict__ hb1, const float* __restrict__ hb2,
        float* __restrict__ spatial) {
    const int b = blockIdx.x;
    const int t = threadIdx.x;          // lane 0..63, one wave per batch
    const float* smx = sp_max + (size_t)b * IMG;
    const float* smn = sp_mean + (size_t)b * IMG;

    float wmax = -FLT_MAX, wsum = 0.f;
    float hmax = -FLT_MAX, hsum = 0.f;
#pragma unroll 4
    for (int i = 0; i < 64; ++i) {
        wmax = fmaxf(wmax, smx[i * 64 + t]);
        wsum += smn[i * 64 + t];
        hmax = fmaxf(hmax, smx[t * 64 + i]);
        hsum += smn[t * 64 + i];
    }
    const float inv = 1.0f / (float)SS;
    float y_w = branch_lane(wsum * inv, wmax, ww0[t], ww1[t], ww2[t], wb0[t], wb1[t], wb2[t]);
    float y_h = branch_lane(hsum * inv, hmax, hw0[t], hw1[t], hw2[t], hb0[t], hb1[t], hb2[t]);

    __shared__ float sh_h[64];
    sh_h[t] = y_h;
    __syncthreads();

    float* sp = spatial + (size_t)b * IMG;
#pragma unroll 4
    for (int h = 0; h < 64; ++h) {
        sp[h * 64 + t] = tanhf(sh_h[h] * y_w);   // coalesced store
    }
}

// ---------------- Kernel 3: apply ----------------
// Non-temporal stores for `out` so the streaming output does NOT allocate in
// L2/L3 — keeps x resident in the 256 MiB Infinity Cache (K1 just read all of
// it), so the x re-read here is L3-hits instead of HBM.
__global__ __launch_bounds__(256) void apply_kernel(const float* __restrict__ x,
                                                    const float* __restrict__ spatial,
                                                    float* __restrict__ out) {
    const int n4 = NTOT / 4;
    const int stride = gridDim.x * blockDim.x;
    for (int i = blockIdx.x * blockDim.x + threadIdx.x; i < n4; i += stride) {
        const size_t base = (size_t)i << 2;            // float index
        f32x4 xv = ((const f32x4*)x)[i];
        const size_t b   = base >> 20;                 // / (C*IMG)
        const size_t pos = base & (IMG - 1);           // index within image
        f32x4 sv = *(const f32x4*)(spatial + (b << 12) + pos);
        f32x4 ov = xv * (sv + 1.0f);
        __builtin_nontemporal_store(ov, ((f32x4*)out) + i);
    }
}

extern "C" void kernel_launch(void* const* d_in, const int* in_sizes, int n_in,
                              void* d_out, int out_size, void* d_ws, size_t ws_size,
                              hipStream_t stream) {
    const float* x   = (const float*)d_in[0];
    const float* ww0 = (const float*)d_in[1];
    const float* ww1 = (const float*)d_in[2];
    const float* ww2 = (const float*)d_in[3];
    const float* wb0 = (const float*)d_in[4];
    const float* wb1 = (const float*)d_in[5];
    const float* wb2 = (const float*)d_in[6];
    const float* hw0 = (const float*)d_in[7];
    const float* hw1 = (const float*)d_in[8];
    const float* hw2 = (const float*)d_in[9];
    const float* hb0 = (const float*)d_in[10];
    const float* hb1 = (const float*)d_in[11];
    const float* hb2 = (const float*)d_in[12];
    float* out = (float*)d_out;

    float* sp_max  = (float*)d_ws;                 // NPIX floats
    float* sp_mean = sp_max + NPIX;                // NPIX floats
    float* spatial = sp_mean + NPIX;               // NPIX floats

    reduce_c_kernel<<<NPIX / 256, 256, 0, stream>>>(x, sp_max, sp_mean);
    branch_kernel<<<BB, 64, 0, stream>>>(sp_max, sp_mean,
                                         ww0, ww1, ww2, wb0, wb1, wb2,
                                         hw0, hw1, hw2, hb0, hb1, hb2, spatial);
    apply_kernel<<<4096, 256, 0, stream>>>(x, spatial, out);
}